// Round 1
// baseline (1100.631 us; speedup 1.0000x reference)
//
#include <hip/hip_runtime.h>
#include <math.h>

#define B_N 2
#define L_N 2048
#define DM 1024
#define DIP 4368      // 2*DI + 2*NST + NH
#define DI 2048
#define CONVD 2304    // DI + 2*NST
#define NH 16
#define HD 128
#define NST 128
#define NC 8
#define CS 256
#define NROWS 4096    // B_N * L_N

__device__ __forceinline__ float silu_f(float x) { return x / (1.f + expf(-x)); }

// ---------------- GEMM: C[M,N] = A[M,K] @ W[N,K]^T (+bias) -----------------
// BM=BN=128, BK=8, 256 threads, 8x8 per thread.
template<int BIAS>
__global__ __launch_bounds__(256) void gemm_nt(const float* __restrict__ A,
                                               const float* __restrict__ W,
                                               const float* __restrict__ bias,
                                               float* __restrict__ C,
                                               int M, int N, int K) {
  __shared__ float As[8][128];
  __shared__ float Bs[8][128];
  const int tid = threadIdx.x;
  const int tx = tid & 15, ty = tid >> 4;
  const int m0 = blockIdx.y * 128, n0 = blockIdx.x * 128;
  const int r = tid >> 1;
  const int kq = (tid & 1) * 4;
  float acc[8][8] = {};
  for (int k0 = 0; k0 < K; k0 += 8) {
    float4 av = *(const float4*)(A + (size_t)(m0 + r) * K + k0 + kq);
    float4 wv = make_float4(0.f, 0.f, 0.f, 0.f);
    if (n0 + r < N) wv = *(const float4*)(W + (size_t)(n0 + r) * K + k0 + kq);
    __syncthreads();
    As[kq + 0][r] = av.x; As[kq + 1][r] = av.y; As[kq + 2][r] = av.z; As[kq + 3][r] = av.w;
    Bs[kq + 0][r] = wv.x; Bs[kq + 1][r] = wv.y; Bs[kq + 2][r] = wv.z; Bs[kq + 3][r] = wv.w;
    __syncthreads();
#pragma unroll
    for (int kk = 0; kk < 8; ++kk) {
      float4 a0 = *(const float4*)&As[kk][ty * 8];
      float4 a1 = *(const float4*)&As[kk][ty * 8 + 4];
      float4 b0 = *(const float4*)&Bs[kk][tx * 8];
      float4 b1 = *(const float4*)&Bs[kk][tx * 8 + 4];
      float a[8] = {a0.x, a0.y, a0.z, a0.w, a1.x, a1.y, a1.z, a1.w};
      float b[8] = {b0.x, b0.y, b0.z, b0.w, b1.x, b1.y, b1.z, b1.w};
#pragma unroll
      for (int i = 0; i < 8; ++i)
#pragma unroll
        for (int j = 0; j < 8; ++j) acc[i][j] = fmaf(a[i], b[j], acc[i][j]);
    }
  }
#pragma unroll
  for (int i = 0; i < 8; ++i) {
    int m = m0 + ty * 8 + i;
#pragma unroll
    for (int j = 0; j < 8; j += 4) {
      int n = n0 + tx * 8 + j;
      if (n < N) {
        float4 v = make_float4(acc[i][j], acc[i][j + 1], acc[i][j + 2], acc[i][j + 3]);
        if (BIAS) { v.x += bias[n]; v.y += bias[n + 1]; v.z += bias[n + 2]; v.w += bias[n + 3]; }
        *(float4*)(C + (size_t)m * N + n) = v;
      }
    }
  }
}

// ---------------- causal depthwise conv1d (k=4) + silu ---------------------
__global__ __launch_bounds__(256) void conv_kernel(const float* __restrict__ zx,
                                                   const float* __restrict__ cw,
                                                   const float* __restrict__ cb,
                                                   float* __restrict__ xcout) {
  int c = blockIdx.x * 256 + threadIdx.x;   // 0..2303
  int ml = blockIdx.y;                      // 0..4095 (b*L + l)
  int l = ml & (L_N - 1);
  const float* src = zx + (size_t)ml * DIP + DI + c;
  float w0 = cw[c * 4 + 0], w1 = cw[c * 4 + 1], w2 = cw[c * 4 + 2], w3 = cw[c * 4 + 3];
  float acc = cb[c] + w3 * src[0];
  if (l >= 1) acc += w2 * src[-(ptrdiff_t)DIP];
  if (l >= 2) acc += w1 * src[-2 * (ptrdiff_t)DIP];
  if (l >= 3) acc += w0 * src[-3 * (ptrdiff_t)DIP];
  xcout[(size_t)ml * CONVD + c] = silu_f(acc);
}

// -------- dt = softplus(raw + bias); dA cumsum per (b,c,h); chunk decay ----
__global__ __launch_bounds__(256) void dtscan_kernel(const float* __restrict__ zx,
                                                     const float* __restrict__ dt_bias,
                                                     const float* __restrict__ A_log,
                                                     float* __restrict__ dts,
                                                     float* __restrict__ acum,
                                                     float* __restrict__ cdec) {
  int bch = blockIdx.x;                 // bc*16 + h
  int h = bch & 15, bc = bch >> 4;
  int i = threadIdx.x;
  int grow = bc * CS + i;
  float raw = zx[(size_t)grow * DIP + DI + CONVD + h] + dt_bias[h];
  float dt = raw > 20.f ? raw : log1pf(expf(raw));
  dts[grow * NH + h] = dt;
  float da = dt * (-expf(A_log[h]));
  __shared__ float sbuf[CS];
  sbuf[i] = da;
  __syncthreads();
  for (int off = 1; off < CS; off <<= 1) {
    float v = (i >= off) ? sbuf[i - off] : 0.f;
    __syncthreads();
    sbuf[i] += v;
    __syncthreads();
  }
  float ac = sbuf[i];
  acum[(size_t)bch * CS + i] = ac;
  if (i == CS - 1) cdec[bch] = expf(ac);
}

// -------- S[b,c,h,i,j] = (i>=j) * exp(ac_i - ac_j) * dot(C_i, B_j) ---------
// CB^T shared across heads; lower-triangle 64x64 tiles only (10 of 16).
__global__ __launch_bounds__(256) void smat_kernel(const float* __restrict__ xc,
                                                   const float* __restrict__ acum,
                                                   float* __restrict__ S) {
  int t = blockIdx.x;                   // 0..9 lower-tri tile id
  int ti = 0, accn = 0;
  while (accn + ti + 1 <= t) { accn += ti + 1; ti++; }
  int tj = t - accn;
  int bc = blockIdx.y;
  int rowbase = bc * CS;
  int i0 = ti * 64, j0 = tj * 64;
  __shared__ float Cst[32][64];
  __shared__ float Bst[32][64];
  int tid = threadIdx.x, tx = tid & 15, ty = tid >> 4;
  float acc[4][4] = {};
  for (int kt = 0; kt < 4; ++kt) {
    int k0 = kt * 32;
    float4 cv[2], bv[2]; int rr[2], kk4[2];
#pragma unroll
    for (int rep = 0; rep < 2; ++rep) {
      int idx = rep * 256 + tid;
      rr[rep] = idx >> 3; kk4[rep] = (idx & 7) * 4;
      cv[rep] = *(const float4*)(xc + (size_t)(rowbase + i0 + rr[rep]) * CONVD + DI + NST + k0 + kk4[rep]);
      bv[rep] = *(const float4*)(xc + (size_t)(rowbase + j0 + rr[rep]) * CONVD + DI + k0 + kk4[rep]);
    }
    __syncthreads();
#pragma unroll
    for (int rep = 0; rep < 2; ++rep) {
      Cst[kk4[rep] + 0][rr[rep]] = cv[rep].x; Cst[kk4[rep] + 1][rr[rep]] = cv[rep].y;
      Cst[kk4[rep] + 2][rr[rep]] = cv[rep].z; Cst[kk4[rep] + 3][rr[rep]] = cv[rep].w;
      Bst[kk4[rep] + 0][rr[rep]] = bv[rep].x; Bst[kk4[rep] + 1][rr[rep]] = bv[rep].y;
      Bst[kk4[rep] + 2][rr[rep]] = bv[rep].z; Bst[kk4[rep] + 3][rr[rep]] = bv[rep].w;
    }
    __syncthreads();
#pragma unroll
    for (int kk = 0; kk < 32; ++kk) {
      float4 c4 = *(const float4*)&Cst[kk][ty * 4];
      float4 b4 = *(const float4*)&Bst[kk][tx * 4];
      float c[4] = {c4.x, c4.y, c4.z, c4.w};
      float b[4] = {b4.x, b4.y, b4.z, b4.w};
#pragma unroll
      for (int i = 0; i < 4; ++i)
#pragma unroll
        for (int j = 0; j < 4; ++j) acc[i][j] = fmaf(c[i], b[j], acc[i][j]);
    }
    __syncthreads();
  }
  const float* ac = acum + (size_t)bc * NH * CS;
  for (int h = 0; h < NH; ++h) {
    float ai[4], aj[4];
#pragma unroll
    for (int i = 0; i < 4; ++i) ai[i] = ac[h * CS + i0 + ty * 4 + i];
#pragma unroll
    for (int j = 0; j < 4; ++j) aj[j] = ac[h * CS + j0 + tx * 4 + j];
    float* Sp = S + ((size_t)bc * NH + h) * CS * CS;
#pragma unroll
    for (int i = 0; i < 4; ++i) {
      int gi = i0 + ty * 4 + i;
      float4 v;
      float o[4];
#pragma unroll
      for (int j = 0; j < 4; ++j) {
        int gj = j0 + tx * 4 + j;
        o[j] = (gi >= gj) ? expf(ai[i] - aj[j]) * acc[i][j] : 0.f;
      }
      v = make_float4(o[0], o[1], o[2], o[3]);
      *(float4*)(Sp + (size_t)gi * CS + j0 + tx * 4) = v;
    }
  }
}

// -------- Y_diag[i,p] = sum_j S[i,j] * x[j,p]*dt[j]  (+ D*x epilogue) ------
__global__ __launch_bounds__(256) void ydiag_kernel(const float* __restrict__ S,
                                                    const float* __restrict__ xc,
                                                    const float* __restrict__ dts,
                                                    const float* __restrict__ Dp,
                                                    float* __restrict__ Y) {
  int bch = blockIdx.y;
  int h = bch & 15, bc = bch >> 4;
  int i0 = blockIdx.x * 64;
  int rowbase = bc * CS;
  __shared__ float Sst[32][64];
  __shared__ float Xs[32][128];
  int tid = threadIdx.x, tx = tid & 15, ty = tid >> 4;
  float acc[4][8] = {};
  int ktiles = (blockIdx.x + 1) * 2;
  const float* Sbase = S + ((size_t)bch * CS + i0) * CS;
  for (int kt = 0; kt < ktiles; ++kt) {
    int k0 = kt * 32;
    float4 sv[2]; int sr[2], skq[2];
#pragma unroll
    for (int rep = 0; rep < 2; ++rep) {
      int idx = rep * 256 + tid;
      sr[rep] = idx >> 3; skq[rep] = (idx & 7) * 4;
      sv[rep] = *(const float4*)(Sbase + (size_t)sr[rep] * CS + k0 + skq[rep]);
    }
    float4 xv[4]; int jr[4], pq[4];
#pragma unroll
    for (int rep = 0; rep < 4; ++rep) {
      int idx = rep * 256 + tid;
      jr[rep] = idx >> 5; pq[rep] = (idx & 31) * 4;
      int grow = rowbase + k0 + jr[rep];
      float dtv = dts[grow * NH + h];
      float4 x4 = *(const float4*)(xc + (size_t)grow * CONVD + h * HD + pq[rep]);
      xv[rep] = make_float4(x4.x * dtv, x4.y * dtv, x4.z * dtv, x4.w * dtv);
    }
    __syncthreads();
#pragma unroll
    for (int rep = 0; rep < 2; ++rep) {
      Sst[skq[rep] + 0][sr[rep]] = sv[rep].x; Sst[skq[rep] + 1][sr[rep]] = sv[rep].y;
      Sst[skq[rep] + 2][sr[rep]] = sv[rep].z; Sst[skq[rep] + 3][sr[rep]] = sv[rep].w;
    }
#pragma unroll
    for (int rep = 0; rep < 4; ++rep) *(float4*)&Xs[jr[rep]][pq[rep]] = xv[rep];
    __syncthreads();
#pragma unroll
    for (int kk = 0; kk < 32; ++kk) {
      float4 s4 = *(const float4*)&Sst[kk][ty * 4];
      float4 x0 = *(const float4*)&Xs[kk][tx * 8];
      float4 x1 = *(const float4*)&Xs[kk][tx * 8 + 4];
      float s[4] = {s4.x, s4.y, s4.z, s4.w};
      float x8[8] = {x0.x, x0.y, x0.z, x0.w, x1.x, x1.y, x1.z, x1.w};
#pragma unroll
      for (int i = 0; i < 4; ++i)
#pragma unroll
        for (int j = 0; j < 8; ++j) acc[i][j] = fmaf(s[i], x8[j], acc[i][j]);
    }
    __syncthreads();
  }
  float Dv = Dp[h];
#pragma unroll
  for (int i = 0; i < 4; ++i) {
    int grow = rowbase + i0 + ty * 4 + i;
#pragma unroll
    for (int j = 0; j < 8; j += 4) {
      int p = tx * 8 + j;
      float4 x4 = *(const float4*)(xc + (size_t)grow * CONVD + h * HD + p);
      float4 v = make_float4(acc[i][j] + Dv * x4.x, acc[i][j + 1] + Dv * x4.y,
                             acc[i][j + 2] + Dv * x4.z, acc[i][j + 3] + Dv * x4.w);
      *(float4*)(Y + (size_t)grow * DI + h * HD + p) = v;
    }
  }
}

// -------- states[n,p] = sum_i B[i,n]*exp(ac_last-ac_i)*x[i,p]*dt[i] --------
__global__ __launch_bounds__(256) void states_kernel(const float* __restrict__ xc,
                                                     const float* __restrict__ dts,
                                                     const float* __restrict__ acum,
                                                     float* __restrict__ st) {
  int bch = blockIdx.x;
  int h = bch & 15, bc = bch >> 4;
  int rowbase = bc * CS;
  __shared__ float Bs[32][128];
  __shared__ float Xs[32][128];
  int tid = threadIdx.x, tx = tid & 15, ty = tid >> 4;
  float acc[8][8] = {};
  const float* ac = acum + (size_t)bch * CS;
  float aclast = ac[CS - 1];
  for (int kt = 0; kt < 8; ++kt) {
    int k0 = kt * 32;
    float4 bv[4], xv[4]; int ir[4], q4[4];
#pragma unroll
    for (int rep = 0; rep < 4; ++rep) {
      int idx = rep * 256 + tid;
      ir[rep] = idx >> 5; q4[rep] = (idx & 31) * 4;
      int grow = rowbase + k0 + ir[rep];
      float dec = expf(aclast - ac[k0 + ir[rep]]);
      float4 b4 = *(const float4*)(xc + (size_t)grow * CONVD + DI + q4[rep]);
      bv[rep] = make_float4(b4.x * dec, b4.y * dec, b4.z * dec, b4.w * dec);
      float dtv = dts[grow * NH + h];
      float4 x4 = *(const float4*)(xc + (size_t)grow * CONVD + h * HD + q4[rep]);
      xv[rep] = make_float4(x4.x * dtv, x4.y * dtv, x4.z * dtv, x4.w * dtv);
    }
    __syncthreads();
#pragma unroll
    for (int rep = 0; rep < 4; ++rep) {
      *(float4*)&Bs[ir[rep]][q4[rep]] = bv[rep];
      *(float4*)&Xs[ir[rep]][q4[rep]] = xv[rep];
    }
    __syncthreads();
#pragma unroll
    for (int kk = 0; kk < 32; ++kk) {
      float4 b0 = *(const float4*)&Bs[kk][ty * 8];
      float4 b1 = *(const float4*)&Bs[kk][ty * 8 + 4];
      float4 x0 = *(const float4*)&Xs[kk][tx * 8];
      float4 x1 = *(const float4*)&Xs[kk][tx * 8 + 4];
      float bb[8] = {b0.x, b0.y, b0.z, b0.w, b1.x, b1.y, b1.z, b1.w};
      float xx[8] = {x0.x, x0.y, x0.z, x0.w, x1.x, x1.y, x1.z, x1.w};
#pragma unroll
      for (int i = 0; i < 8; ++i)
#pragma unroll
        for (int j = 0; j < 8; ++j) acc[i][j] = fmaf(bb[i], xx[j], acc[i][j]);
    }
    __syncthreads();
  }
#pragma unroll
  for (int i = 0; i < 8; ++i) {
    int n = ty * 8 + i;
#pragma unroll
    for (int j = 0; j < 8; j += 4) {
      int p = tx * 8 + j;
      float4 v = make_float4(acc[i][j], acc[i][j + 1], acc[i][j + 2], acc[i][j + 3]);
      *(float4*)(st + ((size_t)bch * NST + n) * HD + p) = v;
    }
  }
}

// -------- sequential scan over chunks: prior_c = state before chunk c ------
__global__ __launch_bounds__(256) void scan_kernel(const float* __restrict__ st,
                                                   const float* __restrict__ cdec,
                                                   float* __restrict__ pr) {
  int gid = blockIdx.x * 256 + threadIdx.x;   // (b,h,n,p)
  int p = gid & 127;
  int n = (gid >> 7) & 127;
  int h = (gid >> 14) & 15;
  int b = gid >> 18;
  float state = 0.f;
  for (int c = 0; c < NC; ++c) {
    int bch = (b * NC + c) * NH + h;
    size_t idx = ((size_t)bch * NST + n) * HD + p;
    pr[idx] = state;
    state = state * cdec[bch] + st[idx];
  }
}

// -------- Y_off[i,p] = exp(ac_i) * sum_n C[i,n] * prior[n,p]  (+= into Y) --
__global__ __launch_bounds__(256) void yoff_kernel(const float* __restrict__ xc,
                                                   const float* __restrict__ pr,
                                                   const float* __restrict__ acum,
                                                   float* __restrict__ Y) {
  int bch = blockIdx.y;
  int h = bch & 15, bc = bch >> 4;
  int i0 = blockIdx.x * 64;
  int rowbase = bc * CS;
  __shared__ float Cst[32][64];
  __shared__ float Ps[32][128];
  int tid = threadIdx.x, tx = tid & 15, ty = tid >> 4;
  float acc[4][8] = {};
  const float* Pbase = pr + (size_t)bch * NST * HD;
  for (int kt = 0; kt < 4; ++kt) {
    int k0 = kt * 32;
    float4 cv[2]; int rr[2], kq[2];
#pragma unroll
    for (int rep = 0; rep < 2; ++rep) {
      int idx = rep * 256 + tid;
      rr[rep] = idx >> 3; kq[rep] = (idx & 7) * 4;
      cv[rep] = *(const float4*)(xc + (size_t)(rowbase + i0 + rr[rep]) * CONVD + DI + NST + k0 + kq[rep]);
    }
    float4 pv[4]; int nr[4], pq[4];
#pragma unroll
    for (int rep = 0; rep < 4; ++rep) {
      int idx = rep * 256 + tid;
      nr[rep] = idx >> 5; pq[rep] = (idx & 31) * 4;
      pv[rep] = *(const float4*)(Pbase + (size_t)(k0 + nr[rep]) * HD + pq[rep]);
    }
    __syncthreads();
#pragma unroll
    for (int rep = 0; rep < 2; ++rep) {
      Cst[kq[rep] + 0][rr[rep]] = cv[rep].x; Cst[kq[rep] + 1][rr[rep]] = cv[rep].y;
      Cst[kq[rep] + 2][rr[rep]] = cv[rep].z; Cst[kq[rep] + 3][rr[rep]] = cv[rep].w;
    }
#pragma unroll
    for (int rep = 0; rep < 4; ++rep) *(float4*)&Ps[nr[rep]][pq[rep]] = pv[rep];
    __syncthreads();
#pragma unroll
    for (int kk = 0; kk < 32; ++kk) {
      float4 c4 = *(const float4*)&Cst[kk][ty * 4];
      float4 p0 = *(const float4*)&Ps[kk][tx * 8];
      float4 p1 = *(const float4*)&Ps[kk][tx * 8 + 4];
      float c[4] = {c4.x, c4.y, c4.z, c4.w};
      float p8[8] = {p0.x, p0.y, p0.z, p0.w, p1.x, p1.y, p1.z, p1.w};
#pragma unroll
      for (int i = 0; i < 4; ++i)
#pragma unroll
        for (int j = 0; j < 8; ++j) acc[i][j] = fmaf(c[i], p8[j], acc[i][j]);
    }
    __syncthreads();
  }
  const float* ac = acum + (size_t)bch * CS;
#pragma unroll
  for (int i = 0; i < 4; ++i) {
    int grow = rowbase + i0 + ty * 4 + i;
    float eai = expf(ac[i0 + ty * 4 + i]);
#pragma unroll
    for (int j = 0; j < 8; j += 4) {
      int p = tx * 8 + j;
      float4 y4 = *(const float4*)(Y + (size_t)grow * DI + h * HD + p);
      y4.x += eai * acc[i][j];     y4.y += eai * acc[i][j + 1];
      y4.z += eai * acc[i][j + 2]; y4.w += eai * acc[i][j + 3];
      *(float4*)(Y + (size_t)grow * DI + h * HD + p) = y4;
    }
  }
}

// -------- y *= silu(z); RMS-normalize over 2048; * norm_w (in-place) -------
__global__ __launch_bounds__(256) void gnorm_kernel(const float* __restrict__ zx,
                                                    const float* __restrict__ nw,
                                                    float* __restrict__ Y) {
  int row = blockIdx.x;
  int tid = threadIdx.x;
  float vals[8];
  float ss = 0.f;
#pragma unroll
  for (int rep = 0; rep < 2; ++rep) {
    int c = tid * 8 + rep * 4;
    float4 yv = *(const float4*)(Y + (size_t)row * DI + c);
    float4 zv = *(const float4*)(zx + (size_t)row * DIP + c);
    float v0 = yv.x * silu_f(zv.x), v1 = yv.y * silu_f(zv.y);
    float v2 = yv.z * silu_f(zv.z), v3 = yv.w * silu_f(zv.w);
    vals[rep * 4 + 0] = v0; vals[rep * 4 + 1] = v1;
    vals[rep * 4 + 2] = v2; vals[rep * 4 + 3] = v3;
    ss += v0 * v0 + v1 * v1 + v2 * v2 + v3 * v3;
  }
  for (int off = 32; off > 0; off >>= 1) ss += __shfl_xor(ss, off);
  __shared__ float wsum[4];
  if ((tid & 63) == 0) wsum[tid >> 6] = ss;
  __syncthreads();
  float scale = rsqrtf((wsum[0] + wsum[1] + wsum[2] + wsum[3]) * (1.f / DI) + 1e-5f);
#pragma unroll
  for (int rep = 0; rep < 2; ++rep) {
    int c = tid * 8 + rep * 4;
    float4 w4 = *(const float4*)(nw + c);
    float4 o = make_float4(vals[rep * 4 + 0] * scale * w4.x, vals[rep * 4 + 1] * scale * w4.y,
                           vals[rep * 4 + 2] * scale * w4.z, vals[rep * 4 + 3] * scale * w4.w);
    *(float4*)(Y + (size_t)row * DI + c) = o;
  }
}

extern "C" void kernel_launch(void* const* d_in, const int* in_sizes, int n_in,
                              void* d_out, int out_size, void* d_ws, size_t ws_size,
                              hipStream_t stream) {
  const float* u          = (const float*)d_in[0];
  const float* in_proj_w  = (const float*)d_in[1];
  const float* conv_w     = (const float*)d_in[2];
  const float* conv_b     = (const float*)d_in[3];
  const float* dt_bias    = (const float*)d_in[4];
  const float* A_log      = (const float*)d_in[5];
  const float* D_param    = (const float*)d_in[6];
  const float* norm_w     = (const float*)d_in[7];
  const float* out_proj_w = (const float*)d_in[8];
  const float* out_proj_b = (const float*)d_in[9];
  float* out = (float*)d_out;
  float* ws  = (float*)d_ws;

  const size_t off_zx = 0;
  const size_t off_xc = off_zx + (size_t)NROWS * DIP;
  const size_t off_dt = off_xc + (size_t)NROWS * CONVD;
  const size_t off_ac = off_dt + (size_t)NROWS * NH;
  const size_t off_cd = off_ac + (size_t)B_N * NC * NH * CS;
  const size_t off_S  = off_cd + 256;
  const size_t off_st = off_S  + (size_t)B_N * NC * NH * CS * CS;
  const size_t off_pr = off_st + (size_t)B_N * NC * NH * NST * HD;
  const size_t off_Y  = off_pr + (size_t)B_N * NC * NH * NST * HD;
  const size_t total  = off_Y  + (size_t)NROWS * DI;
  if (ws_size < total * sizeof(float)) return;   // insufficient scratch

  float* zx   = ws + off_zx;
  float* xc   = ws + off_xc;
  float* dts  = ws + off_dt;
  float* acum = ws + off_ac;
  float* cdec = ws + off_cd;
  float* S    = ws + off_S;
  float* st   = ws + off_st;
  float* pr   = ws + off_pr;
  float* Y    = ws + off_Y;

  // 1. zxbcdt = u @ in_proj_w^T   [4096 x 4368]
  gemm_nt<0><<<dim3(35, 32), 256, 0, stream>>>(u, in_proj_w, nullptr, zx, NROWS, DIP, DM);
  // 2. causal conv1d + silu on xBC slice -> xc [4096 x 2304]
  conv_kernel<<<dim3(9, NROWS), 256, 0, stream>>>(zx, conv_w, conv_b, xc);
  // 3. dt softplus, dA cumsum per chunk, chunk decay
  dtscan_kernel<<<256, 256, 0, stream>>>(zx, dt_bias, A_log, dts, acum, cdec);
  // 4. S = (C B^T) o Lmat (lower tiles, shared dot across heads)
  smat_kernel<<<dim3(10, 16), 256, 0, stream>>>(xc, acum, S);
  // 5. Y_diag = S @ (x*dt)  (+ D*x)
  ydiag_kernel<<<dim3(4, 256), 256, 0, stream>>>(S, xc, dts, D_param, Y);
  // 6. per-chunk states
  states_kernel<<<256, 256, 0, stream>>>(xc, dts, acum, st);
  // 7. scan over chunks
  scan_kernel<<<2048, 256, 0, stream>>>(st, cdec, pr);
  // 8. Y += exp(A_cum) * (C @ prior)
  yoff_kernel<<<dim3(4, 256), 256, 0, stream>>>(xc, pr, acum, Y);
  // 9. gate with silu(z), RMS norm, * norm_w
  gnorm_kernel<<<NROWS, 256, 0, stream>>>(zx, norm_w, Y);
  // 10. out = y @ out_proj_w^T + out_proj_b
  gemm_nt<1><<<dim3(8, 32), 256, 0, stream>>>(Y, out_proj_w, out_proj_b, out, NROWS, DM, DI);
}

// Round 6
// 618.839 us; speedup vs baseline: 1.7785x; 1.7785x over previous
//
#include <hip/hip_runtime.h>
#include <math.h>

#define B_N 2
#define L_N 2048
#define DM 1024
#define DIP 4368      // 2*DI + 2*NST + NH
#define DI 2048
#define CONVD 2304    // DI + 2*NST
#define NH 16
#define HD 128
#define NST 128
#define NC 8
#define CS 256
#define NROWS 4096    // B_N * L_N

typedef __attribute__((ext_vector_type(8))) short short8;
typedef __attribute__((ext_vector_type(4))) float f32x4;

__device__ __forceinline__ float silu_f(float x) { return x / (1.f + expf(-x)); }

__device__ __forceinline__ unsigned short f2bf_rne(float x) {
  unsigned int u = __float_as_uint(x);
  u += 0x7FFFu + ((u >> 16) & 1u);
  return (unsigned short)(u >> 16);
}
__device__ __forceinline__ float bf2f(unsigned short h) {
  return __uint_as_float(((unsigned int)h) << 16);
}

// ------ GEMM via split-bf16 MFMA: C[M,N] = A[M,K] @ W[N,K]^T (+bias) -------
// 128x128 tile, BK=32, 256 thr = 4 waves, each wave a 64x64 sub-tile of
// 4x4 mfma_f32_16x16x32_bf16 fragments. hi/lo split: 3 MFMA passes ~ fp32.
// LDS layout [kb][row][8] bf16 (fragment-linear): ds_read_b128 conflict-free.
template<int BIAS>
__global__ __launch_bounds__(256) void gemm_nt_mfma(const float* __restrict__ A,
                                                    const float* __restrict__ W,
                                                    const float* __restrict__ bias,
                                                    float* __restrict__ C,
                                                    int M, int N, int K) {
  __shared__ unsigned short Ah[4096], Al[4096], Bh[4096], Bl[4096];
  const int tid  = threadIdx.x;
  const int lane = tid & 63;
  const int wave = tid >> 6;
  const int wr = (wave & 1) * 64;
  const int wc = (wave >> 1) * 64;
  const int m0 = blockIdx.y * 128, n0 = blockIdx.x * 128;
  // staging map: thread -> (row, 16 consecutive floats of the 32-wide K-tile)
  const int srow = tid >> 1;
  const int skh  = (tid & 1) * 16;   // float offset in K-tile
  const int skb0 = (tid & 1) * 2;    // first 8-wide k-block index
  const bool wvalid = (n0 + srow) < N;
  const float* Ap = A + (size_t)(m0 + srow) * K + skh;
  const float* Wp = W + (size_t)(n0 + srow) * K + skh;

  f32x4 acc[4][4] = {};

  const int ntiles = K >> 5;
  for (int kt = 0; kt < ntiles; ++kt) {
    const float* As = Ap + kt * 32;
    const float* Ws = Wp + kt * 32;
    float ab[16], wb[16];
    *(float4*)&ab[0]  = *(const float4*)(As + 0);
    *(float4*)&ab[4]  = *(const float4*)(As + 4);
    *(float4*)&ab[8]  = *(const float4*)(As + 8);
    *(float4*)&ab[12] = *(const float4*)(As + 12);
    if (wvalid) {
      *(float4*)&wb[0]  = *(const float4*)(Ws + 0);
      *(float4*)&wb[4]  = *(const float4*)(Ws + 4);
      *(float4*)&wb[8]  = *(const float4*)(Ws + 8);
      *(float4*)&wb[12] = *(const float4*)(Ws + 12);
    } else {
#pragma unroll
      for (int j = 0; j < 16; ++j) wb[j] = 0.f;
    }
    __syncthreads();   // previous iteration's LDS reads done
#pragma unroll
    for (int c = 0; c < 2; ++c) {
      const int kb = skb0 + c;
      const int off = (kb * 128 + srow) * 8;
      short8 hv, lv;
#pragma unroll
      for (int j = 0; j < 8; ++j) {
        float x = ab[c * 8 + j];
        unsigned short h = f2bf_rne(x);
        hv[j] = (short)h;
        lv[j] = (short)f2bf_rne(x - bf2f(h));
      }
      *(short8*)&Ah[off] = hv;
      *(short8*)&Al[off] = lv;
#pragma unroll
      for (int j = 0; j < 8; ++j) {
        float x = wb[c * 8 + j];
        unsigned short h = f2bf_rne(x);
        hv[j] = (short)h;
        lv[j] = (short)f2bf_rne(x - bf2f(h));
      }
      *(short8*)&Bh[off] = hv;
      *(short8*)&Bl[off] = lv;
    }
    __syncthreads();
    // fragment reads: lane l -> row (l&15), k-block (l>>4)
    const int fra = ((lane >> 4) * 128 + wr + (lane & 15)) * 8;
    const int frb = ((lane >> 4) * 128 + wc + (lane & 15)) * 8;
    short8 ah[4], al[4];
#pragma unroll
    for (int mi = 0; mi < 4; ++mi) {
      ah[mi] = *(const short8*)&Ah[fra + mi * 128];
      al[mi] = *(const short8*)&Al[fra + mi * 128];
    }
#pragma unroll
    for (int ni = 0; ni < 4; ++ni) {
      short8 bh = *(const short8*)&Bh[frb + ni * 128];
      short8 bl = *(const short8*)&Bl[frb + ni * 128];
#pragma unroll
      for (int mi = 0; mi < 4; ++mi) {
        acc[mi][ni] = __builtin_amdgcn_mfma_f32_16x16x32_bf16(ah[mi], bh, acc[mi][ni], 0, 0, 0);
        acc[mi][ni] = __builtin_amdgcn_mfma_f32_16x16x32_bf16(ah[mi], bl, acc[mi][ni], 0, 0, 0);
        acc[mi][ni] = __builtin_amdgcn_mfma_f32_16x16x32_bf16(al[mi], bh, acc[mi][ni], 0, 0, 0);
      }
    }
  }
  // epilogue: D row = (lane>>4)*4 + r, col = lane&15  (m89-verified mapping)
#pragma unroll
  for (int ni = 0; ni < 4; ++ni) {
    int gcolb = n0 + wc + ni * 16;
    if (gcolb >= N) continue;            // N % 16 == 0 for both gemms
    int gcol = gcolb + (lane & 15);
    float bv = BIAS ? bias[gcol] : 0.f;
#pragma unroll
    for (int mi = 0; mi < 4; ++mi) {
      int growb = m0 + wr + mi * 16 + (lane >> 4) * 4;
#pragma unroll
      for (int r = 0; r < 4; ++r) {
        C[(size_t)(growb + r) * N + gcol] = acc[mi][ni][r] + bv;
      }
    }
  }
}

// ---------------- causal depthwise conv1d (k=4) + silu ---------------------
__global__ __launch_bounds__(256) void conv_kernel(const float* __restrict__ zx,
                                                   const float* __restrict__ cw,
                                                   const float* __restrict__ cb,
                                                   float* __restrict__ xcout) {
  int c = blockIdx.x * 256 + threadIdx.x;   // 0..2303
  int ml = blockIdx.y;                      // 0..4095 (b*L + l)
  int l = ml & (L_N - 1);
  const float* src = zx + (size_t)ml * DIP + DI + c;
  float w0 = cw[c * 4 + 0], w1 = cw[c * 4 + 1], w2 = cw[c * 4 + 2], w3 = cw[c * 4 + 3];
  float acc = cb[c] + w3 * src[0];
  if (l >= 1) acc += w2 * src[-(ptrdiff_t)DIP];
  if (l >= 2) acc += w1 * src[-2 * (ptrdiff_t)DIP];
  if (l >= 3) acc += w0 * src[-3 * (ptrdiff_t)DIP];
  xcout[(size_t)ml * CONVD + c] = silu_f(acc);
}

// -------- dt = softplus(raw + bias); dA cumsum per (b,c,h); chunk decay ----
__global__ __launch_bounds__(256) void dtscan_kernel(const float* __restrict__ zx,
                                                     const float* __restrict__ dt_bias,
                                                     const float* __restrict__ A_log,
                                                     float* __restrict__ dts,
                                                     float* __restrict__ acum,
                                                     float* __restrict__ cdec) {
  int bch = blockIdx.x;                 // bc*16 + h
  int h = bch & 15, bc = bch >> 4;
  int i = threadIdx.x;
  int grow = bc * CS + i;
  float raw = zx[(size_t)grow * DIP + DI + CONVD + h] + dt_bias[h];
  float dt = raw > 20.f ? raw : log1pf(expf(raw));
  dts[grow * NH + h] = dt;
  float da = dt * (-expf(A_log[h]));
  __shared__ float sbuf[CS];
  sbuf[i] = da;
  __syncthreads();
  for (int off = 1; off < CS; off <<= 1) {
    float v = (i >= off) ? sbuf[i - off] : 0.f;
    __syncthreads();
    sbuf[i] += v;
    __syncthreads();
  }
  float ac = sbuf[i];
  acum[(size_t)bch * CS + i] = ac;
  if (i == CS - 1) cdec[bch] = expf(ac);
}

// -------- S[b,c,h,i,j] = (i>=j) * exp(ac_i - ac_j) * dot(C_i, B_j) ---------
// CB^T shared across heads; lower-triangle 64x64 tiles only (10 of 16).
__global__ __launch_bounds__(256) void smat_kernel(const float* __restrict__ xc,
                                                   const float* __restrict__ acum,
                                                   float* __restrict__ S) {
  int t = blockIdx.x;                   // 0..9 lower-tri tile id
  int ti = 0, accn = 0;
  while (accn + ti + 1 <= t) { accn += ti + 1; ti++; }
  int tj = t - accn;
  int bc = blockIdx.y;
  int rowbase = bc * CS;
  int i0 = ti * 64, j0 = tj * 64;
  __shared__ float Cst[32][64];
  __shared__ float Bst[32][64];
  int tid = threadIdx.x, tx = tid & 15, ty = tid >> 4;
  float acc[4][4] = {};
  for (int kt = 0; kt < 4; ++kt) {
    int k0 = kt * 32;
    float4 cv[2], bv[2]; int rr[2], kk4[2];
#pragma unroll
    for (int rep = 0; rep < 2; ++rep) {
      int idx = rep * 256 + tid;
      rr[rep] = idx >> 3; kk4[rep] = (idx & 7) * 4;
      cv[rep] = *(const float4*)(xc + (size_t)(rowbase + i0 + rr[rep]) * CONVD + DI + NST + k0 + kk4[rep]);
      bv[rep] = *(const float4*)(xc + (size_t)(rowbase + j0 + rr[rep]) * CONVD + DI + k0 + kk4[rep]);
    }
    __syncthreads();
#pragma unroll
    for (int rep = 0; rep < 2; ++rep) {
      Cst[kk4[rep] + 0][rr[rep]] = cv[rep].x; Cst[kk4[rep] + 1][rr[rep]] = cv[rep].y;
      Cst[kk4[rep] + 2][rr[rep]] = cv[rep].z; Cst[kk4[rep] + 3][rr[rep]] = cv[rep].w;
      Bst[kk4[rep] + 0][rr[rep]] = bv[rep].x; Bst[kk4[rep] + 1][rr[rep]] = bv[rep].y;
      Bst[kk4[rep] + 2][rr[rep]] = bv[rep].z; Bst[kk4[rep] + 3][rr[rep]] = bv[rep].w;
    }
    __syncthreads();
#pragma unroll
    for (int kk = 0; kk < 32; ++kk) {
      float4 c4 = *(const float4*)&Cst[kk][ty * 4];
      float4 b4 = *(const float4*)&Bst[kk][tx * 4];
      float c[4] = {c4.x, c4.y, c4.z, c4.w};
      float b[4] = {b4.x, b4.y, b4.z, b4.w};
#pragma unroll
      for (int i = 0; i < 4; ++i)
#pragma unroll
        for (int j = 0; j < 4; ++j) acc[i][j] = fmaf(c[i], b[j], acc[i][j]);
    }
    __syncthreads();
  }
  const float* ac = acum + (size_t)bc * NH * CS;
  for (int h = 0; h < NH; ++h) {
    float ai[4], aj[4];
#pragma unroll
    for (int i = 0; i < 4; ++i) ai[i] = ac[h * CS + i0 + ty * 4 + i];
#pragma unroll
    for (int j = 0; j < 4; ++j) aj[j] = ac[h * CS + j0 + tx * 4 + j];
    float* Sp = S + ((size_t)bc * NH + h) * CS * CS;
#pragma unroll
    for (int i = 0; i < 4; ++i) {
      int gi = i0 + ty * 4 + i;
      float o[4];
#pragma unroll
      for (int j = 0; j < 4; ++j) {
        int gj = j0 + tx * 4 + j;
        o[j] = (gi >= gj) ? expf(ai[i] - aj[j]) * acc[i][j] : 0.f;
      }
      *(float4*)(Sp + (size_t)gi * CS + j0 + tx * 4) = make_float4(o[0], o[1], o[2], o[3]);
    }
  }
}

// -------- Y_diag[i,p] = sum_j S[i,j] * x[j,p]*dt[j]  (+ D*x epilogue) ------
__global__ __launch_bounds__(256) void ydiag_kernel(const float* __restrict__ S,
                                                    const float* __restrict__ xc,
                                                    const float* __restrict__ dts,
                                                    const float* __restrict__ Dp,
                                                    float* __restrict__ Y) {
  int bch = blockIdx.y;
  int h = bch & 15, bc = bch >> 4;
  int i0 = blockIdx.x * 64;
  int rowbase = bc * CS;
  __shared__ float Sst[32][64];
  __shared__ float Xs[32][128];
  int tid = threadIdx.x, tx = tid & 15, ty = tid >> 4;
  float acc[4][8] = {};
  int ktiles = (blockIdx.x + 1) * 2;
  const float* Sbase = S + ((size_t)bch * CS + i0) * CS;
  for (int kt = 0; kt < ktiles; ++kt) {
    int k0 = kt * 32;
    float4 sv[2]; int sr[2], skq[2];
#pragma unroll
    for (int rep = 0; rep < 2; ++rep) {
      int idx = rep * 256 + tid;
      sr[rep] = idx >> 3; skq[rep] = (idx & 7) * 4;
      sv[rep] = *(const float4*)(Sbase + (size_t)sr[rep] * CS + k0 + skq[rep]);
    }
    float4 xv[4]; int jr[4], pq[4];
#pragma unroll
    for (int rep = 0; rep < 4; ++rep) {
      int idx = rep * 256 + tid;
      jr[rep] = idx >> 5; pq[rep] = (idx & 31) * 4;
      int grow = rowbase + k0 + jr[rep];
      float dtv = dts[grow * NH + h];
      float4 x4 = *(const float4*)(xc + (size_t)grow * CONVD + h * HD + pq[rep]);
      xv[rep] = make_float4(x4.x * dtv, x4.y * dtv, x4.z * dtv, x4.w * dtv);
    }
    __syncthreads();
#pragma unroll
    for (int rep = 0; rep < 2; ++rep) {
      Sst[skq[rep] + 0][sr[rep]] = sv[rep].x; Sst[skq[rep] + 1][sr[rep]] = sv[rep].y;
      Sst[skq[rep] + 2][sr[rep]] = sv[rep].z; Sst[skq[rep] + 3][sr[rep]] = sv[rep].w;
    }
#pragma unroll
    for (int rep = 0; rep < 4; ++rep) *(float4*)&Xs[jr[rep]][pq[rep]] = xv[rep];
    __syncthreads();
#pragma unroll
    for (int kk = 0; kk < 32; ++kk) {
      float4 s4 = *(const float4*)&Sst[kk][ty * 4];
      float4 x0 = *(const float4*)&Xs[kk][tx * 8];
      float4 x1 = *(const float4*)&Xs[kk][tx * 8 + 4];
      float s[4] = {s4.x, s4.y, s4.z, s4.w};
      float x8[8] = {x0.x, x0.y, x0.z, x0.w, x1.x, x1.y, x1.z, x1.w};
#pragma unroll
      for (int i = 0; i < 4; ++i)
#pragma unroll
        for (int j = 0; j < 8; ++j) acc[i][j] = fmaf(s[i], x8[j], acc[i][j]);
    }
    __syncthreads();
  }
  float Dv = Dp[h];
#pragma unroll
  for (int i = 0; i < 4; ++i) {
    int grow = rowbase + i0 + ty * 4 + i;
#pragma unroll
    for (int j = 0; j < 8; j += 4) {
      int p = tx * 8 + j;
      float4 x4 = *(const float4*)(xc + (size_t)grow * CONVD + h * HD + p);
      float4 v = make_float4(acc[i][j] + Dv * x4.x, acc[i][j + 1] + Dv * x4.y,
                             acc[i][j + 2] + Dv * x4.z, acc[i][j + 3] + Dv * x4.w);
      *(float4*)(Y + (size_t)grow * DI + h * HD + p) = v;
    }
  }
}

// -------- states[n,p] = sum_i B[i,n]*exp(ac_last-ac_i)*x[i,p]*dt[i] --------
__global__ __launch_bounds__(256) void states_kernel(const float* __restrict__ xc,
                                                     const float* __restrict__ dts,
                                                     const float* __restrict__ acum,
                                                     float* __restrict__ st) {
  int bch = blockIdx.x;
  int h = bch & 15, bc = bch >> 4;
  int rowbase = bc * CS;
  __shared__ float Bs[32][128];
  __shared__ float Xs[32][128];
  int tid = threadIdx.x, tx = tid & 15, ty = tid >> 4;
  float acc[8][8] = {};
  const float* ac = acum + (size_t)bch * CS;
  float aclast = ac[CS - 1];
  for (int kt = 0; kt < 8; ++kt) {
    int k0 = kt * 32;
    float4 bv[4], xv[4]; int ir[4], q4[4];
#pragma unroll
    for (int rep = 0; rep < 4; ++rep) {
      int idx = rep * 256 + tid;
      ir[rep] = idx >> 5; q4[rep] = (idx & 31) * 4;
      int grow = rowbase + k0 + ir[rep];
      float dec = expf(aclast - ac[k0 + ir[rep]]);
      float4 b4 = *(const float4*)(xc + (size_t)grow * CONVD + DI + q4[rep]);
      bv[rep] = make_float4(b4.x * dec, b4.y * dec, b4.z * dec, b4.w * dec);
      float dtv = dts[grow * NH + h];
      float4 x4 = *(const float4*)(xc + (size_t)grow * CONVD + h * HD + q4[rep]);
      xv[rep] = make_float4(x4.x * dtv, x4.y * dtv, x4.z * dtv, x4.w * dtv);
    }
    __syncthreads();
#pragma unroll
    for (int rep = 0; rep < 4; ++rep) {
      *(float4*)&Bs[ir[rep]][q4[rep]] = bv[rep];
      *(float4*)&Xs[ir[rep]][q4[rep]] = xv[rep];
    }
    __syncthreads();
#pragma unroll
    for (int kk = 0; kk < 32; ++kk) {
      float4 b0 = *(const float4*)&Bs[kk][ty * 8];
      float4 b1 = *(const float4*)&Bs[kk][ty * 8 + 4];
      float4 x0 = *(const float4*)&Xs[kk][tx * 8];
      float4 x1 = *(const float4*)&Xs[kk][tx * 8 + 4];
      float bb[8] = {b0.x, b0.y, b0.z, b0.w, b1.x, b1.y, b1.z, b1.w};
      float xx[8] = {x0.x, x0.y, x0.z, x0.w, x1.x, x1.y, x1.z, x1.w};
#pragma unroll
      for (int i = 0; i < 8; ++i)
#pragma unroll
        for (int j = 0; j < 8; ++j) acc[i][j] = fmaf(bb[i], xx[j], acc[i][j]);
    }
    __syncthreads();
  }
#pragma unroll
  for (int i = 0; i < 8; ++i) {
    int n = ty * 8 + i;
#pragma unroll
    for (int j = 0; j < 8; j += 4) {
      int p = tx * 8 + j;
      float4 v = make_float4(acc[i][j], acc[i][j + 1], acc[i][j + 2], acc[i][j + 3]);
      *(float4*)(st + ((size_t)bch * NST + n) * HD + p) = v;
    }
  }
}

// -------- sequential scan over chunks: prior_c = state before chunk c ------
__global__ __launch_bounds__(256) void scan_kernel(const float* __restrict__ st,
                                                   const float* __restrict__ cdec,
                                                   float* __restrict__ pr) {
  int gid = blockIdx.x * 256 + threadIdx.x;   // (b,h,n,p)
  int p = gid & 127;
  int n = (gid >> 7) & 127;
  int h = (gid >> 14) & 15;
  int b = gid >> 18;
  float state = 0.f;
  for (int c = 0; c < NC; ++c) {
    int bch = (b * NC + c) * NH + h;
    size_t idx = ((size_t)bch * NST + n) * HD + p;
    pr[idx] = state;
    state = state * cdec[bch] + st[idx];
  }
}

// -------- Y_off[i,p] = exp(ac_i) * sum_n C[i,n] * prior[n,p]  (+= into Y) --
__global__ __launch_bounds__(256) void yoff_kernel(const float* __restrict__ xc,
                                                   const float* __restrict__ pr,
                                                   const float* __restrict__ acum,
                                                   float* __restrict__ Y) {
  int bch = blockIdx.y;
  int h = bch & 15, bc = bch >> 4;
  int i0 = blockIdx.x * 64;
  int rowbase = bc * CS;
  __shared__ float Cst[32][64];
  __shared__ float Ps[32][128];
  int tid = threadIdx.x, tx = tid & 15, ty = tid >> 4;
  float acc[4][8] = {};
  const float* Pbase = pr + (size_t)bch * NST * HD;
  for (int kt = 0; kt < 4; ++kt) {
    int k0 = kt * 32;
    float4 cv[2]; int rr[2], kq[2];
#pragma unroll
    for (int rep = 0; rep < 2; ++rep) {
      int idx = rep * 256 + tid;
      rr[rep] = idx >> 3; kq[rep] = (idx & 7) * 4;
      cv[rep] = *(const float4*)(xc + (size_t)(rowbase + i0 + rr[rep]) * CONVD + DI + NST + k0 + kq[rep]);
    }
    float4 pv[4]; int nr[4], pq[4];
#pragma unroll
    for (int rep = 0; rep < 4; ++rep) {
      int idx = rep * 256 + tid;
      nr[rep] = idx >> 5; pq[rep] = (idx & 31) * 4;
      pv[rep] = *(const float4*)(Pbase + (size_t)(k0 + nr[rep]) * HD + pq[rep]);
    }
    __syncthreads();
#pragma unroll
    for (int rep = 0; rep < 2; ++rep) {
      Cst[kq[rep] + 0][rr[rep]] = cv[rep].x; Cst[kq[rep] + 1][rr[rep]] = cv[rep].y;
      Cst[kq[rep] + 2][rr[rep]] = cv[rep].z; Cst[kq[rep] + 3][rr[rep]] = cv[rep].w;
    }
#pragma unroll
    for (int rep = 0; rep < 4; ++rep) *(float4*)&Ps[nr[rep]][pq[rep]] = pv[rep];
    __syncthreads();
#pragma unroll
    for (int kk = 0; kk < 32; ++kk) {
      float4 c4 = *(const float4*)&Cst[kk][ty * 4];
      float4 p0 = *(const float4*)&Ps[kk][tx * 8];
      float4 p1 = *(const float4*)&Ps[kk][tx * 8 + 4];
      float c[4] = {c4.x, c4.y, c4.z, c4.w};
      float p8[8] = {p0.x, p0.y, p0.z, p0.w, p1.x, p1.y, p1.z, p1.w};
#pragma unroll
      for (int i = 0; i < 4; ++i)
#pragma unroll
        for (int j = 0; j < 8; ++j) acc[i][j] = fmaf(c[i], p8[j], acc[i][j]);
    }
    __syncthreads();
  }
  const float* ac = acum + (size_t)bch * CS;
#pragma unroll
  for (int i = 0; i < 4; ++i) {
    int grow = rowbase + i0 + ty * 4 + i;
    float eai = expf(ac[i0 + ty * 4 + i]);
#pragma unroll
    for (int j = 0; j < 8; j += 4) {
      int p = tx * 8 + j;
      float4 y4 = *(const float4*)(Y + (size_t)grow * DI + h * HD + p);
      y4.x += eai * acc[i][j];     y4.y += eai * acc[i][j + 1];
      y4.z += eai * acc[i][j + 2]; y4.w += eai * acc[i][j + 3];
      *(float4*)(Y + (size_t)grow * DI + h * HD + p) = y4;
    }
  }
}

// -------- y *= silu(z); RMS-normalize over 2048; * norm_w (in-place) -------
__global__ __launch_bounds__(256) void gnorm_kernel(const float* __restrict__ zx,
                                                    const float* __restrict__ nw,
                                                    float* __restrict__ Y) {
  int row = blockIdx.x;
  int tid = threadIdx.x;
  float vals[8];
  float ss = 0.f;
#pragma unroll
  for (int rep = 0; rep < 2; ++rep) {
    int c = tid * 8 + rep * 4;
    float4 yv = *(const float4*)(Y + (size_t)row * DI + c);
    float4 zv = *(const float4*)(zx + (size_t)row * DIP + c);
    float v0 = yv.x * silu_f(zv.x), v1 = yv.y * silu_f(zv.y);
    float v2 = yv.z * silu_f(zv.z), v3 = yv.w * silu_f(zv.w);
    vals[rep * 4 + 0] = v0; vals[rep * 4 + 1] = v1;
    vals[rep * 4 + 2] = v2; vals[rep * 4 + 3] = v3;
    ss += v0 * v0 + v1 * v1 + v2 * v2 + v3 * v3;
  }
  for (int off = 32; off > 0; off >>= 1) ss += __shfl_xor(ss, off);
  __shared__ float wsum[4];
  if ((tid & 63) == 0) wsum[tid >> 6] = ss;
  __syncthreads();
  float scale = rsqrtf((wsum[0] + wsum[1] + wsum[2] + wsum[3]) * (1.f / DI) + 1e-5f);
#pragma unroll
  for (int rep = 0; rep < 2; ++rep) {
    int c = tid * 8 + rep * 4;
    float4 w4 = *(const float4*)(nw + c);
    float4 o = make_float4(vals[rep * 4 + 0] * scale * w4.x, vals[rep * 4 + 1] * scale * w4.y,
                           vals[rep * 4 + 2] * scale * w4.z, vals[rep * 4 + 3] * scale * w4.w);
    *(float4*)(Y + (size_t)row * DI + c) = o;
  }
}

extern "C" void kernel_launch(void* const* d_in, const int* in_sizes, int n_in,
                              void* d_out, int out_size, void* d_ws, size_t ws_size,
                              hipStream_t stream) {
  const float* u          = (const float*)d_in[0];
  const float* in_proj_w  = (const float*)d_in[1];
  const float* conv_w     = (const float*)d_in[2];
  const float* conv_b     = (const float*)d_in[3];
  const float* dt_bias    = (const float*)d_in[4];
  const float* A_log      = (const float*)d_in[5];
  const float* D_param    = (const float*)d_in[6];
  const float* norm_w     = (const float*)d_in[7];
  const float* out_proj_w = (const float*)d_in[8];
  const float* out_proj_b = (const float*)d_in[9];
  float* out = (float*)d_out;
  float* ws  = (float*)d_ws;

  const size_t off_zx = 0;
  const size_t off_xc = off_zx + (size_t)NROWS * DIP;
  const size_t off_dt = off_xc + (size_t)NROWS * CONVD;
  const size_t off_ac = off_dt + (size_t)NROWS * NH;
  const size_t off_cd = off_ac + (size_t)B_N * NC * NH * CS;
  const size_t off_S  = off_cd + 256;
  const size_t off_st = off_S  + (size_t)B_N * NC * NH * CS * CS;
  const size_t off_pr = off_st + (size_t)B_N * NC * NH * NST * HD;
  const size_t off_Y  = off_pr + (size_t)B_N * NC * NH * NST * HD;
  const size_t total  = off_Y  + (size_t)NROWS * DI;
  if (ws_size < total * sizeof(float)) return;   // insufficient scratch

  float* zx   = ws + off_zx;
  float* xc   = ws + off_xc;
  float* dts  = ws + off_dt;
  float* acum = ws + off_ac;
  float* cdec = ws + off_cd;
  float* S    = ws + off_S;
  float* st   = ws + off_st;
  float* pr   = ws + off_pr;
  float* Y    = ws + off_Y;

  // 1. zxbcdt = u @ in_proj_w^T   [4096 x 4368]  (split-bf16 MFMA)
  gemm_nt_mfma<0><<<dim3(35, 32), 256, 0, stream>>>(u, in_proj_w, nullptr, zx, NROWS, DIP, DM);
  // 2. causal conv1d + silu on xBC slice -> xc [4096 x 2304]
  conv_kernel<<<dim3(9, NROWS), 256, 0, stream>>>(zx, conv_w, conv_b, xc);
  // 3. dt softplus, dA cumsum per chunk, chunk decay
  dtscan_kernel<<<256, 256, 0, stream>>>(zx, dt_bias, A_log, dts, acum, cdec);
  // 4. S = (C B^T) o Lmat (lower tiles, shared dot across heads)
  smat_kernel<<<dim3(10, 16), 256, 0, stream>>>(xc, acum, S);
  // 5. Y_diag = S @ (x*dt)  (+ D*x)
  ydiag_kernel<<<dim3(4, 256), 256, 0, stream>>>(S, xc, dts, D_param, Y);
  // 6. per-chunk states
  states_kernel<<<256, 256, 0, stream>>>(xc, dts, acum, st);
  // 7. scan over chunks
  scan_kernel<<<2048, 256, 0, stream>>>(st, cdec, pr);
  // 8. Y += exp(A_cum) * (C @ prior)
  yoff_kernel<<<dim3(4, 256), 256, 0, stream>>>(xc, pr, acum, Y);
  // 9. gate with silu(z), RMS norm, * norm_w
  gnorm_kernel<<<NROWS, 256, 0, stream>>>(zx, norm_w, Y);
  // 10. out = y @ out_proj_w^T + out_proj_b  (split-bf16 MFMA)
  gemm_nt_mfma<1><<<dim3(8, 32), 256, 0, stream>>>(Y, out_proj_w, out_proj_b, out, NROWS, DM, DI);
}